// Round 5
// baseline (4617.780 us; speedup 1.0000x reference)
//
#include <hip/hip_runtime.h>

// LightGCN 2-layer propagation on MI355X — R5: bucketed LDS-accumulate gather,
// no exact CSR at all.
//
// R4 post-mortem: k_fill is traffic-bound, not latency-bound: WRITE_SIZE
// 246 MB = 4M random 4 B writes x 64 B line eviction, ~0.7 TB/s. ILP didn't
// help (378 -> 358 us). Fix: remove the random-write kernel entirely.
//
// R5 pipeline:
//   1) k_part: partition 4M (dst,src) entries into 586 buckets of 256
//      consecutive dst nodes, packed 4 B each (local<<18 | nbr). Only 586
//      bucket tails are being written -> lines fill before eviction.
//   2) k_lgather1: one WG per bucket, 256x64 f32 accumulator in LDS (64 KB);
//      per entry: coalesced 256 B row read + ds_add_f32 (2 lanes/bank, free).
//      Writes y1 -> d_out coalesced.
//   3) k_lgather2 (x2, 32-column halves, 32 KB acc) + k_copy_half, as R3.
// ws = entries 17.4 MB + bcnt + half 19.2 MB ~= 36.6 MB (R3-proven budget).

#define NUM_USERS 100000
#define NUM_ITEMS 50000
#define N_NODES   150000
#define NUM_EDGES 2000000
#define EMB_D     64

#define BSH   8                                   // 256 nodes per bucket
#define BNODES 256
#define NBUCK ((N_NODES + BNODES - 1) / BNODES)   // 586
#define BCAP  7424   // mean 6827, sd ~83 -> +7 sigma; data is fixed-seed

// ---- 1) partition entries into buckets ----
__global__ __launch_bounds__(256) void k_part(const int* __restrict__ eidx,
                                              int* __restrict__ bcnt,
                                              unsigned* __restrict__ entries) {
    const int H = NUM_EDGES / 2;
    int t = blockIdx.x * blockDim.x + threadIdx.x;
    if (t >= H) return;
    int r0 = eidx[t],     c0 = eidx[NUM_EDGES + t];
    int r1 = eidx[t + H], c1 = eidx[NUM_EDGES + t + H];
    int b0 = r0 >> BSH, b1 = c0 >> BSH, b2 = r1 >> BSH, b3 = c1 >> BSH;
    // all returning atomics issued before any store consumes a result
    int p0 = atomicAdd(&bcnt[b0], 1);
    int p1 = atomicAdd(&bcnt[b1], 1);
    int p2 = atomicAdd(&bcnt[b2], 1);
    int p3 = atomicAdd(&bcnt[b3], 1);
    if (p0 < BCAP) entries[(size_t)b0 * BCAP + p0] = ((unsigned)(r0 & 255) << 18) | (unsigned)c0;
    if (p1 < BCAP) entries[(size_t)b1 * BCAP + p1] = ((unsigned)(c0 & 255) << 18) | (unsigned)r0;
    if (p2 < BCAP) entries[(size_t)b2 * BCAP + p2] = ((unsigned)(r1 & 255) << 18) | (unsigned)c1;
    if (p3 < BCAP) entries[(size_t)b3 * BCAP + p3] = ((unsigned)(c1 & 255) << 18) | (unsigned)r1;
}

// ---- 2) layer-1 gather: one WG per bucket, full-width LDS accumulator ----
__global__ __launch_bounds__(512) void k_lgather1(const unsigned* __restrict__ entries,
                                                  const int* __restrict__ bcnt,
                                                  const float* __restrict__ user,
                                                  const float* __restrict__ item,
                                                  float* __restrict__ out) {
    __shared__ float acc[BNODES * EMB_D];   // 64 KB -> 2 blocks/CU
    int b = blockIdx.x;
    int tid = threadIdx.x;
    int cnt = min(bcnt[b], BCAP);

    for (int i = tid; i < BNODES * EMB_D; i += 512) acc[i] = 0.f;
    __syncthreads();

    int wid = tid >> 6, lane = tid & 63;    // 8 waves
    const unsigned* eb = entries + (size_t)b * BCAP;
    for (int j0 = wid * 8; j0 < cnt; j0 += 8 * 8) {
#pragma unroll
        for (int p = 0; p < 8; ++p) {
            int j = j0 + p;
            if (j < cnt) {
                unsigned e = eb[j];
                int nbr = e & 0x3FFFF;
                int loc = e >> 18;
                const float* x = (nbr < NUM_USERS)
                    ? user + (size_t)nbr * EMB_D
                    : item + (size_t)(nbr - NUM_USERS) * EMB_D;
                atomicAdd(&acc[loc * EMB_D + lane], x[lane]);
            }
        }
    }
    __syncthreads();

    int base = b << BSH;
    for (int i = tid; i < BNODES * EMB_D; i += 512) {
        int node = base + (i >> 6);
        if (node < N_NODES) out[(size_t)node * EMB_D + (i & 63)] = 0.5f * acc[i];
    }
}

// ---- 3) layer-2 half gather: 32-column accumulator, 2 entries per wave ----
__global__ __launch_bounds__(512) void k_lgather2(const unsigned* __restrict__ entries,
                                                  const int* __restrict__ bcnt,
                                                  const float* __restrict__ x,
                                                  int coloff,
                                                  float* __restrict__ halfout) {
    __shared__ float acc[BNODES * 32];      // 32 KB
    int b = blockIdx.x;
    int tid = threadIdx.x;
    int cnt = min(bcnt[b], BCAP);

    for (int i = tid; i < BNODES * 32; i += 512) acc[i] = 0.f;
    __syncthreads();

    int wid = tid >> 6;
    int sub = (tid >> 5) & 1;               // which entry of the pair
    int d = tid & 31;                       // dim within half
    const unsigned* eb = entries + (size_t)b * BCAP;
    for (int j0 = wid * 8; j0 < cnt; j0 += 8 * 8) {
#pragma unroll
        for (int p = 0; p < 4; ++p) {
            int j = j0 + p * 2 + sub;
            if (j < cnt) {
                unsigned e = eb[j];
                int nbr = e & 0x3FFFF;
                int loc = e >> 18;
                atomicAdd(&acc[loc * 32 + d], x[(size_t)nbr * EMB_D + coloff + d]);
            }
        }
    }
    __syncthreads();

    int base = b << BSH;
    for (int i = tid; i < BNODES * 32; i += 512) {
        int node = base + (i >> 5);
        if (node < N_NODES) halfout[(size_t)node * 32 + (i & 31)] = 0.5f * acc[i];
    }
}

// ---- 4) copy half buffer [N,32] into d_out columns [coloff, coloff+32) ----
__global__ __launch_bounds__(256) void k_copy_half(const float* __restrict__ half,
                                                   float* __restrict__ out,
                                                   int coloff) {
    int gid = blockIdx.x * blockDim.x + threadIdx.x;   // one per float4
    const int total = N_NODES * 32 / 4;                // 1.2M
    if (gid >= total) return;
    int node = gid >> 3;
    int q = (gid & 7) * 4;
    float4 v = *(const float4*)(half + (size_t)node * 32 + q);
    *(float4*)(out + (size_t)node * EMB_D + coloff + q) = v;
}

extern "C" void kernel_launch(void* const* d_in, const int* in_sizes, int n_in,
                              void* d_out, int out_size, void* d_ws, size_t ws_size,
                              hipStream_t stream) {
    const int*   eidx = (const int*)d_in[0];     // [2, NUM_EDGES] int32
    const float* user = (const float*)d_in[1];   // [NUM_USERS, 64]
    const float* item = (const float*)d_in[2];   // [NUM_ITEMS, 64]
    float*       out  = (float*)d_out;           // [N_NODES, 64]

    // workspace layout — total ~36.6 MB (R3 proved ~36.4 MB is safe)
    char* ws = (char*)d_ws;
    size_t off = 0;
    auto alloc = [&](size_t bytes) {
        char* p = ws + off;
        off += (bytes + 255) & ~(size_t)255;
        return p;
    };
    unsigned* entries = (unsigned*)alloc((size_t)NBUCK * BCAP * sizeof(unsigned)); // 17.4 MB
    int*      bcnt    = (int*)alloc((size_t)NBUCK * sizeof(int));                  // 2.3 KB
    float*    half    = (float*)alloc((size_t)N_NODES * 32 * sizeof(float));       // 19.2 MB

    hipMemsetAsync(bcnt, 0, (size_t)NBUCK * sizeof(int), stream);

    const int B = 256;
    const int H = NUM_EDGES / 2;

    k_part<<<(H + B - 1) / B, B, 0, stream>>>(eidx, bcnt, entries);

    // layer 1: y1 (f32) -> d_out
    k_lgather1<<<NBUCK, 512, 0, stream>>>(entries, bcnt, user, item, out);

    // layer 2, per 32-column half
    const int gcp = ((N_NODES * 32 / 4) + B - 1) / B;
    k_lgather2<<<NBUCK, 512, 0, stream>>>(entries, bcnt, out, 0, half);
    k_copy_half<<<gcp, B, 0, stream>>>(half, out, 0);
    k_lgather2<<<NBUCK, 512, 0, stream>>>(entries, bcnt, out, 32, half);
    k_copy_half<<<gcp, B, 0, stream>>>(half, out, 32);
}

// Round 6
// 723.698 us; speedup vs baseline: 6.3808x; 6.3808x over previous
//
#include <hip/hip_runtime.h>

// LightGCN 2-layer propagation on MI355X — R6: bucketed exact-CSR build +
// R4-style global gathers.
//
// R5 post-mortem: LDS-accumulate gather at 586 WGs is latency-serialized
// (1712 us, HBM 3.7%, VALU 5.5%) — reverted. Gathers stay R3/R4-style
// (150K waves). R4 post-mortem: k_fill was traffic-bound (246 MB random-line
// writes). R6 fix: partition entries into 586 node-range buckets first
// (sequential tail writes), then build the exact CSR per bucket in LDS and
// place into the bucket's CONTIGUOUS ~27 KB adj segment -> write lines fill
// before eviction (adj traffic ~16 MB, not 246 MB). Also removes hist + big
// scans. bcnt padded 1 counter / 64 B line (L2 same-line atomic serialization).
// ws: union(entries 17.4 MB, half 19.2 MB) + adj 16 + start/deg 1.2 = 36.4 MB.

#define NUM_USERS 100000
#define NUM_ITEMS 50000
#define N_NODES   150000
#define NUM_EDGES 2000000
#define EMB_D     64

#define BSH    8                                   // 256 nodes per bucket
#define BNODES 256
#define NBUCK  ((N_NODES + BNODES - 1) / BNODES)   // 586
#define BCAP   7424     // mean 6827, sd ~83 -> +7 sigma (fixed-seed data)
#define CPAD   16       // bcnt stride in ints: one counter per 64 B line

// ---- 1) partition (dst,src) entries into dst-range buckets ----
__global__ __launch_bounds__(256) void k_part(const int* __restrict__ eidx,
                                              int* __restrict__ bcnt,
                                              unsigned* __restrict__ entries) {
    const int H = NUM_EDGES / 2;
    int t = blockIdx.x * blockDim.x + threadIdx.x;
    if (t >= H) return;
    int r0 = eidx[t],     c0 = eidx[NUM_EDGES + t];
    int r1 = eidx[t + H], c1 = eidx[NUM_EDGES + t + H];
    int b0 = r0 >> BSH, b1 = c0 >> BSH, b2 = r1 >> BSH, b3 = c1 >> BSH;
    int p0 = atomicAdd(&bcnt[b0 * CPAD], 1);
    int p1 = atomicAdd(&bcnt[b1 * CPAD], 1);
    int p2 = atomicAdd(&bcnt[b2 * CPAD], 1);
    int p3 = atomicAdd(&bcnt[b3 * CPAD], 1);
    if (p0 < BCAP) entries[(size_t)b0 * BCAP + p0] = ((unsigned)(r0 & 255) << 18) | (unsigned)c0;
    if (p1 < BCAP) entries[(size_t)b1 * BCAP + p1] = ((unsigned)(c0 & 255) << 18) | (unsigned)r0;
    if (p2 < BCAP) entries[(size_t)b2 * BCAP + p2] = ((unsigned)(r1 & 255) << 18) | (unsigned)c1;
    if (p3 < BCAP) entries[(size_t)b3 * BCAP + p3] = ((unsigned)(c1 & 255) << 18) | (unsigned)r1;
}

// ---- 2) exclusive scan of 586 clamped bucket counts ----
__global__ __launch_bounds__(1024) void k_bscan(const int* __restrict__ bcnt,
                                                int* __restrict__ bstart) {
    __shared__ int lds[1024];
    int t = threadIdx.x;
    int v = (t < NBUCK) ? min(bcnt[t * CPAD], BCAP) : 0;
    lds[t] = v;
    __syncthreads();
    int val = v;
    for (int off = 1; off < 1024; off <<= 1) {
        int add = (t >= off) ? lds[t - off] : 0;
        __syncthreads();
        val += add;
        lds[t] = val;
        __syncthreads();
    }
    if (t < NBUCK) bstart[t] = val - v;
}

// ---- 3) per-bucket exact CSR: LDS histogram + scan, place into contiguous
//         adj segment; emit global start/deg per node ----
__global__ __launch_bounds__(512) void k_fill_local(const unsigned* __restrict__ entries,
                                                    const int* __restrict__ bcnt,
                                                    const int* __restrict__ bstart,
                                                    int* __restrict__ adj,
                                                    int* __restrict__ start_g,
                                                    int* __restrict__ deg_g) {
    __shared__ int lhist[BNODES];
    __shared__ int lcur[BNODES];
    int b = blockIdx.x, tid = threadIdx.x;
    int cnt = min(bcnt[b * CPAD], BCAP);
    const unsigned* eb = entries + (size_t)b * BCAP;

    if (tid < BNODES) lhist[tid] = 0;
    __syncthreads();
    for (int j = tid; j < cnt; j += 512) atomicAdd(&lhist[eb[j] >> 18], 1);
    __syncthreads();

    // Hillis-Steele inclusive scan of lhist into lcur (first 256 threads)
    if (tid < BNODES) lcur[tid] = lhist[tid];
    __syncthreads();
    for (int off = 1; off < BNODES; off <<= 1) {
        int add = 0;
        if (tid < BNODES && tid >= off) add = lcur[tid - off];
        __syncthreads();
        if (tid < BNODES) lcur[tid] += add;
        __syncthreads();
    }

    int gbase = bstart[b];
    if (tid < BNODES) {
        int st = lcur[tid] - lhist[tid];          // exclusive
        int node = (b << BSH) + tid;
        if (node < N_NODES) {
            start_g[node] = gbase + st;
            deg_g[node] = lhist[tid];
        }
        lcur[tid] = st;                           // reuse as cursor
    }
    __syncthreads();

    for (int j = tid; j < cnt; j += 512) {
        unsigned e = eb[j];
        int loc = e >> 18;
        int nbr = e & 0x3FFFF;
        int p = atomicAdd(&lcur[loc], 1);
        adj[(size_t)gbase + p] = nbr;             // random only within ~27 KB
    }
}

// ---- 4) layer-1 gather: one 64-lane wave per node, lane = dim ----
__global__ __launch_bounds__(256) void k_gather64(const int* __restrict__ adj,
                                                  const int* __restrict__ start_g,
                                                  const int* __restrict__ deg_g,
                                                  const float* __restrict__ user,
                                                  const float* __restrict__ item,
                                                  float* __restrict__ out) {
    int wid = (blockIdx.x * blockDim.x + threadIdx.x) >> 6;
    int lane = threadIdx.x & 63;
    if (wid >= N_NODES) return;

    int start = start_g[wid];
    int end = start + deg_g[wid];
    float acc = 0.f;

    int j = start;
    for (; j + 4 <= end; j += 4) {
        int n0 = adj[j + 0], n1 = adj[j + 1], n2 = adj[j + 2], n3 = adj[j + 3];
        const float* p0 = (n0 < NUM_USERS) ? user + (size_t)n0 * EMB_D
                                           : item + (size_t)(n0 - NUM_USERS) * EMB_D;
        const float* p1 = (n1 < NUM_USERS) ? user + (size_t)n1 * EMB_D
                                           : item + (size_t)(n1 - NUM_USERS) * EMB_D;
        const float* p2 = (n2 < NUM_USERS) ? user + (size_t)n2 * EMB_D
                                           : item + (size_t)(n2 - NUM_USERS) * EMB_D;
        const float* p3 = (n3 < NUM_USERS) ? user + (size_t)n3 * EMB_D
                                           : item + (size_t)(n3 - NUM_USERS) * EMB_D;
        acc += p0[lane];
        acc += p1[lane];
        acc += p2[lane];
        acc += p3[lane];
    }
    for (; j < end; ++j) {
        int n = adj[j];
        const float* p = (n < NUM_USERS) ? user + (size_t)n * EMB_D
                                         : item + (size_t)(n - NUM_USERS) * EMB_D;
        acc += p[lane];
    }
    out[(size_t)wid * EMB_D + lane] = 0.5f * acc;
}

// ---- 5) layer-2 half gather: 32 lanes per node ----
__global__ __launch_bounds__(256) void k_gather_half(const int* __restrict__ adj,
                                                     const int* __restrict__ start_g,
                                                     const int* __restrict__ deg_g,
                                                     const float* __restrict__ x,
                                                     int coloff,
                                                     float* __restrict__ halfout) {
    int gid = blockIdx.x * blockDim.x + threadIdx.x;
    int node = gid >> 5;
    int d = gid & 31;
    if (node >= N_NODES) return;

    int start = start_g[node];
    int end = start + deg_g[node];
    float acc = 0.f;

    int j = start;
    for (; j + 4 <= end; j += 4) {
        int n0 = adj[j + 0], n1 = adj[j + 1], n2 = adj[j + 2], n3 = adj[j + 3];
        acc += x[(size_t)n0 * EMB_D + coloff + d];
        acc += x[(size_t)n1 * EMB_D + coloff + d];
        acc += x[(size_t)n2 * EMB_D + coloff + d];
        acc += x[(size_t)n3 * EMB_D + coloff + d];
    }
    for (; j < end; ++j) {
        int n = adj[j];
        acc += x[(size_t)n * EMB_D + coloff + d];
    }
    halfout[(size_t)node * 32 + d] = 0.5f * acc;
}

// ---- 6) copy half buffer [N,32] into d_out columns [coloff, coloff+32) ----
__global__ __launch_bounds__(256) void k_copy_half(const float* __restrict__ half,
                                                   float* __restrict__ out,
                                                   int coloff) {
    int gid = blockIdx.x * blockDim.x + threadIdx.x;   // one per float4
    const int total = N_NODES * 32 / 4;
    if (gid >= total) return;
    int node = gid >> 3;
    int q = (gid & 7) * 4;
    float4 v = *(const float4*)(half + (size_t)node * 32 + q);
    *(float4*)(out + (size_t)node * EMB_D + coloff + q) = v;
}

extern "C" void kernel_launch(void* const* d_in, const int* in_sizes, int n_in,
                              void* d_out, int out_size, void* d_ws, size_t ws_size,
                              hipStream_t stream) {
    const int*   eidx = (const int*)d_in[0];     // [2, NUM_EDGES] int32
    const float* user = (const float*)d_in[1];   // [NUM_USERS, 64]
    const float* item = (const float*)d_in[2];   // [NUM_ITEMS, 64]
    float*       out  = (float*)d_out;           // [N_NODES, 64]

    // workspace — total ~36.4 MB (R3-proven footprint)
    char* ws = (char*)d_ws;
    size_t off = 0;
    auto alloc = [&](size_t bytes) {
        char* p = ws + off;
        off += (bytes + 255) & ~(size_t)255;
        return p;
    };
    // union: entries (17.4 MB, dead after k_fill_local) / half (19.2 MB, layer 2)
    char*     uni     = alloc((size_t)N_NODES * 32 * sizeof(float));          // 19.2 MB
    unsigned* entries = (unsigned*)uni;
    float*    half    = (float*)uni;
    int*      adj     = (int*)alloc((size_t)4 * NUM_EDGES * sizeof(int));     // 16 MB
    int*      start_g = (int*)alloc((size_t)N_NODES * sizeof(int));           // 0.6 MB
    int*      deg_g   = (int*)alloc((size_t)N_NODES * sizeof(int));           // 0.6 MB
    int*      bcnt    = (int*)alloc((size_t)NBUCK * CPAD * sizeof(int));      // 37.5 KB
    int*      bstart  = (int*)alloc((size_t)NBUCK * sizeof(int));             // 2.3 KB

    hipMemsetAsync(bcnt, 0, (size_t)NBUCK * CPAD * sizeof(int), stream);

    const int B = 256;
    const int H = NUM_EDGES / 2;

    // CSR build: partition -> bucket scan -> local exact fill
    k_part<<<(H + B - 1) / B, B, 0, stream>>>(eidx, bcnt, entries);
    k_bscan<<<1, 1024, 0, stream>>>(bcnt, bstart);
    k_fill_local<<<NBUCK, 512, 0, stream>>>(entries, bcnt, bstart, adj, start_g, deg_g);

    // layer 1: y1 (f32) -> d_out
    const int g64 = ((N_NODES * 64) + B - 1) / B;
    k_gather64<<<g64, B, 0, stream>>>(adj, start_g, deg_g, user, item, out);

    // layer 2, per 32-column half (entries buffer is dead now; half aliases it)
    const int g32 = ((N_NODES * 32) + B - 1) / B;
    const int gcp = ((N_NODES * 32 / 4) + B - 1) / B;

    k_gather_half<<<g32, B, 0, stream>>>(adj, start_g, deg_g, out, 0, half);
    k_copy_half<<<gcp, B, 0, stream>>>(half, out, 0);
    k_gather_half<<<g32, B, 0, stream>>>(adj, start_g, deg_g, out, 32, half);
    k_copy_half<<<gcp, B, 0, stream>>>(half, out, 32);
}

// Round 7
// 623.203 us; speedup vs baseline: 7.4098x; 1.1613x over previous
//
#include <hip/hip_runtime.h>

// LightGCN 2-layer propagation on MI355X — R7: deterministic 3-pass bucket
// partition (no global atomics) + column-blocked gathers (no copy kernels).
//
// R6 post-mortem: k_part = 285 us, WRITE_SIZE 204 MB — the 586 bucket tails
// were appended from all 8 XCDs concurrently; non-coherent per-XCD L2s made
// every 4 B append cost a full line write-back (cross-XCD ping-pong).
// R7 fix: radix-style 3 passes. Each of 128 producer blocks owns a contiguous
// edge chunk; (A) LDS histogram -> cnt[b][g]; (B) exact scan -> slice offsets;
// (C) scatter into private (bucket,block) slices — one writer per slice,
// sequential fill, ~16-25 MB writes, fully deterministic, no BCAP padding.
//
// Column-blocked layers: L1-half (user/item -> half buf [N,32]) then L2-half
// (half buf -> out columns) per 32-col half; removes both k_copy_half and
// reads the same HBM lines (128 B of a row = exactly 2 of its 4 lines).
//
// ws: union(entries 16 MB, half 19.2 MB) + adj 16 + start/deg 1.2 + cnt 0.3
//   ~= 36.7 MB (R3 proved ~36.4 MB safe; ws_size >= out rounded up).

#define NUM_USERS 100000
#define NUM_ITEMS 50000
#define N_NODES   150000
#define NUM_EDGES 2000000
#define EMB_D     64

#define BSH    8                                   // 256 nodes per bucket
#define BNODES 256
#define NBUCK  ((N_NODES + BNODES - 1) / BNODES)   // 586
#define P      128                                 // producer blocks
#define CE     ((NUM_EDGES + P - 1) / P)           // 15625 edges per block
#define NTOT   (NBUCK * P)                         // 75008 count entries

// ---- A) per-block bucket histogram ----
__global__ __launch_bounds__(256) void k_count(const int* __restrict__ eidx,
                                               int* __restrict__ cnt) {
    __shared__ int hist[NBUCK];
    int g = blockIdx.x, tid = threadIdx.x;
    for (int b = tid; b < NBUCK; b += 256) hist[b] = 0;
    __syncthreads();
    int lo = g * CE, hi = min(NUM_EDGES, lo + CE);
    for (int j = lo + tid; j < hi; j += 256) {
        int r = eidx[j], c = eidx[NUM_EDGES + j];
        atomicAdd(&hist[r >> BSH], 1);
        atomicAdd(&hist[c >> BSH], 1);
    }
    __syncthreads();
    for (int b = tid; b < NBUCK; b += 256) cnt[b * P + g] = hist[b];
}

// ---- B) exclusive scan of cnt (bucket-major, 75008 elements) in place ----
__global__ __launch_bounds__(1024) void k_scan(int* __restrict__ cnt) {
    __shared__ int lds[1024];
    const int CHUNK = (NTOT + 1023) / 1024;        // 74
    int t = threadIdx.x;
    int i0 = t * CHUNK, i1 = min(NTOT, i0 + CHUNK);
    int s = 0;
    for (int i = i0; i < i1; ++i) s += cnt[i];
    lds[t] = s;
    __syncthreads();
    int val = s;
    for (int off = 1; off < 1024; off <<= 1) {
        int add = (t >= off) ? lds[t - off] : 0;
        __syncthreads();
        val += add;
        lds[t] = val;
        __syncthreads();
    }
    int run = val - s;                             // exclusive base
    for (int i = i0; i < i1; ++i) {
        int v = cnt[i];
        cnt[i] = run;
        run += v;
    }
}

// ---- C) scatter entries into private (bucket, block) slices ----
__global__ __launch_bounds__(256) void k_scatter(const int* __restrict__ eidx,
                                                 const int* __restrict__ cofs,
                                                 unsigned* __restrict__ entries) {
    __shared__ int lcur[NBUCK];
    int g = blockIdx.x, tid = threadIdx.x;
    for (int b = tid; b < NBUCK; b += 256) lcur[b] = cofs[b * P + g];
    __syncthreads();
    int lo = g * CE, hi = min(NUM_EDGES, lo + CE);
    for (int j = lo + tid; j < hi; j += 256) {
        int r = eidx[j], c = eidx[NUM_EDGES + j];
        int p = atomicAdd(&lcur[r >> BSH], 1);
        entries[p] = ((unsigned)(r & 255) << 18) | (unsigned)c;
        int q = atomicAdd(&lcur[c >> BSH], 1);
        entries[q] = ((unsigned)(c & 255) << 18) | (unsigned)r;
    }
}

// ---- D) per-bucket exact CSR: LDS histogram + scan, contiguous adj place ----
__global__ __launch_bounds__(512) void k_fill_local(const unsigned* __restrict__ entries,
                                                    const int* __restrict__ cofs,
                                                    int* __restrict__ adj,
                                                    int* __restrict__ start_g,
                                                    int* __restrict__ deg_g) {
    __shared__ int lhist[BNODES];
    __shared__ int lcur[BNODES];
    int b = blockIdx.x, tid = threadIdx.x;
    int gbase = cofs[b * P];
    int gnext = (b + 1 < NBUCK) ? cofs[(b + 1) * P] : 2 * NUM_EDGES;
    int cnt = gnext - gbase;
    const unsigned* eb = entries + gbase;

    if (tid < BNODES) lhist[tid] = 0;
    __syncthreads();
    for (int j = tid; j < cnt; j += 512) atomicAdd(&lhist[eb[j] >> 18], 1);
    __syncthreads();

    if (tid < BNODES) lcur[tid] = lhist[tid];
    __syncthreads();
    for (int off = 1; off < BNODES; off <<= 1) {
        int add = 0;
        if (tid < BNODES && tid >= off) add = lcur[tid - off];
        __syncthreads();
        if (tid < BNODES) lcur[tid] += add;
        __syncthreads();
    }

    if (tid < BNODES) {
        int st = lcur[tid] - lhist[tid];           // exclusive
        int node = (b << BSH) + tid;
        if (node < N_NODES) {
            start_g[node] = gbase + st;
            deg_g[node] = lhist[tid];
        }
        lcur[tid] = st;
    }
    __syncthreads();

    for (int j = tid; j < cnt; j += 512) {
        unsigned e = eb[j];
        int p = atomicAdd(&lcur[e >> 18], 1);
        adj[(size_t)gbase + p] = (int)(e & 0x3FFFF); // random only within ~27 KB
    }
}

// ---- E) layer-1 half gather: user/item cols [c,c+32) -> half buf [N,32] ----
__global__ __launch_bounds__(256) void k_gh1(const int* __restrict__ adj,
                                             const int* __restrict__ start_g,
                                             const int* __restrict__ deg_g,
                                             const float* __restrict__ user,
                                             const float* __restrict__ item,
                                             int coloff,
                                             float* __restrict__ half) {
    int gid = blockIdx.x * blockDim.x + threadIdx.x;
    int node = gid >> 5;
    int d = gid & 31;
    if (node >= N_NODES) return;

    int start = start_g[node];
    int end = start + deg_g[node];
    float acc = 0.f;

    int j = start;
    for (; j + 4 <= end; j += 4) {
        int n0 = adj[j + 0], n1 = adj[j + 1], n2 = adj[j + 2], n3 = adj[j + 3];
        const float* p0 = (n0 < NUM_USERS) ? user + (size_t)n0 * EMB_D
                                           : item + (size_t)(n0 - NUM_USERS) * EMB_D;
        const float* p1 = (n1 < NUM_USERS) ? user + (size_t)n1 * EMB_D
                                           : item + (size_t)(n1 - NUM_USERS) * EMB_D;
        const float* p2 = (n2 < NUM_USERS) ? user + (size_t)n2 * EMB_D
                                           : item + (size_t)(n2 - NUM_USERS) * EMB_D;
        const float* p3 = (n3 < NUM_USERS) ? user + (size_t)n3 * EMB_D
                                           : item + (size_t)(n3 - NUM_USERS) * EMB_D;
        acc += p0[coloff + d];
        acc += p1[coloff + d];
        acc += p2[coloff + d];
        acc += p3[coloff + d];
    }
    for (; j < end; ++j) {
        int n = adj[j];
        const float* p = (n < NUM_USERS) ? user + (size_t)n * EMB_D
                                         : item + (size_t)(n - NUM_USERS) * EMB_D;
        acc += p[coloff + d];
    }
    half[(size_t)node * 32 + d] = 0.5f * acc;
}

// ---- F) layer-2 half gather: half buf [N,32] -> out cols [c,c+32) ----
__global__ __launch_bounds__(256) void k_gh2(const int* __restrict__ adj,
                                             const int* __restrict__ start_g,
                                             const int* __restrict__ deg_g,
                                             const float* __restrict__ half,
                                             int coloff,
                                             float* __restrict__ out) {
    int gid = blockIdx.x * blockDim.x + threadIdx.x;
    int node = gid >> 5;
    int d = gid & 31;
    if (node >= N_NODES) return;

    int start = start_g[node];
    int end = start + deg_g[node];
    float acc = 0.f;

    int j = start;
    for (; j + 4 <= end; j += 4) {
        int n0 = adj[j + 0], n1 = adj[j + 1], n2 = adj[j + 2], n3 = adj[j + 3];
        acc += half[(size_t)n0 * 32 + d];
        acc += half[(size_t)n1 * 32 + d];
        acc += half[(size_t)n2 * 32 + d];
        acc += half[(size_t)n3 * 32 + d];
    }
    for (; j < end; ++j) {
        int n = adj[j];
        acc += half[(size_t)n * 32 + d];
    }
    out[(size_t)node * EMB_D + coloff + d] = 0.5f * acc;
}

extern "C" void kernel_launch(void* const* d_in, const int* in_sizes, int n_in,
                              void* d_out, int out_size, void* d_ws, size_t ws_size,
                              hipStream_t stream) {
    const int*   eidx = (const int*)d_in[0];     // [2, NUM_EDGES] int32
    const float* user = (const float*)d_in[1];   // [NUM_USERS, 64]
    const float* item = (const float*)d_in[2];   // [NUM_ITEMS, 64]
    float*       out  = (float*)d_out;           // [N_NODES, 64]

    // workspace — ~36.7 MB
    char* ws = (char*)d_ws;
    size_t off = 0;
    auto alloc = [&](size_t bytes) {
        char* p = ws + off;
        off += (bytes + 255) & ~(size_t)255;
        return p;
    };
    // union: entries (16 MB, dead after k_fill_local) / half (19.2 MB, gathers)
    char*     uni     = alloc((size_t)N_NODES * 32 * sizeof(float));          // 19.2 MB
    unsigned* entries = (unsigned*)uni;
    float*    half    = (float*)uni;
    int*      adj     = (int*)alloc((size_t)4 * NUM_EDGES * sizeof(int));     // 16 MB
    int*      start_g = (int*)alloc((size_t)N_NODES * sizeof(int));           // 0.6 MB
    int*      deg_g   = (int*)alloc((size_t)N_NODES * sizeof(int));           // 0.6 MB
    int*      cnt     = (int*)alloc((size_t)NTOT * sizeof(int));              // 0.3 MB

    // CSR build: count -> scan -> scatter -> local fill (no global atomics)
    k_count<<<P, 256, 0, stream>>>(eidx, cnt);
    k_scan<<<1, 1024, 0, stream>>>(cnt);
    k_scatter<<<P, 256, 0, stream>>>(eidx, cnt, entries);
    k_fill_local<<<NBUCK, 512, 0, stream>>>(entries, cnt, adj, start_g, deg_g);

    // column-blocked 2-layer propagation (entries dead; half aliases it)
    const int ggh = ((N_NODES * 32) + 255) / 256;  // 18750 blocks
    k_gh1<<<ggh, 256, 0, stream>>>(adj, start_g, deg_g, user, item, 0, half);
    k_gh2<<<ggh, 256, 0, stream>>>(adj, start_g, deg_g, half, 0, out);
    k_gh1<<<ggh, 256, 0, stream>>>(adj, start_g, deg_g, user, item, 32, half);
    k_gh2<<<ggh, 256, 0, stream>>>(adj, start_g, deg_g, half, 32, out);
}

// Round 8
// 497.983 us; speedup vs baseline: 9.2730x; 1.2515x over previous
//
#include <hip/hip_runtime.h>

// LightGCN 2-layer propagation on MI355X — R8: R7 structure with a parallel
// 3-kernel scan and full-chip producer grid.
//
// R7 post-mortem: top dispatch was k_scan = 117 us — a SINGLE BLOCK scanning
// 75008 counts (occupancy 0.15%, HBM 0.05%): pure serial latency on an idle
// GPU. Also k_count/k_scatter ran at P=128 blocks (half the CUs idle).
// R8: (1) hierarchical scan: 293-block local scan (1024 elems/block) ->
// 1-block scan of 293 partials -> offset add. (2) P=512 producer blocks
// (CE=3907) so partition kernels use all 256 CUs. NTOT = 586*512 = 300032
// = 293*1024 exactly.
//
// ws: union(entries 16 MB, half 19.2 MB) + adj 16 + start/deg 1.2 + cnt 1.2
//   + partials ~= 37.6 MB.

#define NUM_USERS 100000
#define NUM_ITEMS 50000
#define N_NODES   150000
#define NUM_EDGES 2000000
#define EMB_D     64

#define BSH    8                                   // 256 nodes per bucket
#define BNODES 256
#define NBUCK  ((N_NODES + BNODES - 1) / BNODES)   // 586
#define P      512                                 // producer blocks
#define CE     ((NUM_EDGES + P - 1) / P)           // 3907 edges per block
#define NTOT   (NBUCK * P)                         // 300032 = 293 * 1024
#define SBLK   (NTOT / 1024)                       // 293 scan blocks

// ---- A) per-block bucket histogram ----
__global__ __launch_bounds__(256) void k_count(const int* __restrict__ eidx,
                                               int* __restrict__ cnt) {
    __shared__ int hist[NBUCK];
    int g = blockIdx.x, tid = threadIdx.x;
    for (int b = tid; b < NBUCK; b += 256) hist[b] = 0;
    __syncthreads();
    int lo = g * CE, hi = min(NUM_EDGES, lo + CE);
    for (int j = lo + tid; j < hi; j += 256) {
        int r = eidx[j], c = eidx[NUM_EDGES + j];
        atomicAdd(&hist[r >> BSH], 1);
        atomicAdd(&hist[c >> BSH], 1);
    }
    __syncthreads();
    for (int b = tid; b < NBUCK; b += 256) cnt[b * P + g] = hist[b];
}

// ---- B1) local exclusive scan: 1024 elems/block (256 thr x 4) ----
__global__ __launch_bounds__(256) void k_scan1(int* __restrict__ cnt,
                                               int* __restrict__ blocksums) {
    __shared__ int lds[256];
    int base = blockIdx.x * 1024 + threadIdx.x * 4;
    int v0 = cnt[base + 0], v1 = cnt[base + 1], v2 = cnt[base + 2], v3 = cnt[base + 3];
    int t = v0 + v1 + v2 + v3;
    lds[threadIdx.x] = t;
    __syncthreads();
    int val = t;
    for (int off = 1; off < 256; off <<= 1) {
        int add = (threadIdx.x >= off) ? lds[threadIdx.x - off] : 0;
        __syncthreads();
        val += add;
        lds[threadIdx.x] = val;
        __syncthreads();
    }
    int run = val - t;
    cnt[base + 0] = run; run += v0;
    cnt[base + 1] = run; run += v1;
    cnt[base + 2] = run; run += v2;
    cnt[base + 3] = run;
    if (threadIdx.x == 255) blocksums[blockIdx.x] = val;
}

// ---- B2) 1-block exclusive scan of 293 partials ----
__global__ __launch_bounds__(512) void k_scan2(const int* __restrict__ blocksums,
                                               int* __restrict__ blockoffs) {
    __shared__ int lds[512];
    int t = threadIdx.x;
    int v = (t < SBLK) ? blocksums[t] : 0;
    lds[t] = v;
    __syncthreads();
    int val = v;
    for (int off = 1; off < 512; off <<= 1) {
        int add = (t >= off) ? lds[t - off] : 0;
        __syncthreads();
        val += add;
        lds[t] = val;
        __syncthreads();
    }
    if (t < SBLK) blockoffs[t] = val - v;
}

// ---- B3) add block offsets ----
__global__ __launch_bounds__(256) void k_scan3(int* __restrict__ cnt,
                                               const int* __restrict__ blockoffs) {
    int i = blockIdx.x * blockDim.x + threadIdx.x;
    if (i < NTOT) cnt[i] += blockoffs[i >> 10];
}

// ---- C) scatter entries into private (bucket, block) slices ----
__global__ __launch_bounds__(256) void k_scatter(const int* __restrict__ eidx,
                                                 const int* __restrict__ cofs,
                                                 unsigned* __restrict__ entries) {
    __shared__ int lcur[NBUCK];
    int g = blockIdx.x, tid = threadIdx.x;
    for (int b = tid; b < NBUCK; b += 256) lcur[b] = cofs[b * P + g];
    __syncthreads();
    int lo = g * CE, hi = min(NUM_EDGES, lo + CE);
    for (int j = lo + tid; j < hi; j += 256) {
        int r = eidx[j], c = eidx[NUM_EDGES + j];
        int p = atomicAdd(&lcur[r >> BSH], 1);
        entries[p] = ((unsigned)(r & 255) << 18) | (unsigned)c;
        int q = atomicAdd(&lcur[c >> BSH], 1);
        entries[q] = ((unsigned)(c & 255) << 18) | (unsigned)r;
    }
}

// ---- D) per-bucket exact CSR: LDS histogram + scan, contiguous adj place ----
__global__ __launch_bounds__(512) void k_fill_local(const unsigned* __restrict__ entries,
                                                    const int* __restrict__ cofs,
                                                    int* __restrict__ adj,
                                                    int* __restrict__ start_g,
                                                    int* __restrict__ deg_g) {
    __shared__ int lhist[BNODES];
    __shared__ int lcur[BNODES];
    int b = blockIdx.x, tid = threadIdx.x;
    int gbase = cofs[b * P];
    int gnext = (b + 1 < NBUCK) ? cofs[(b + 1) * P] : 2 * NUM_EDGES;
    int cnt = gnext - gbase;
    const unsigned* eb = entries + gbase;

    if (tid < BNODES) lhist[tid] = 0;
    __syncthreads();
    for (int j = tid; j < cnt; j += 512) atomicAdd(&lhist[eb[j] >> 18], 1);
    __syncthreads();

    if (tid < BNODES) lcur[tid] = lhist[tid];
    __syncthreads();
    for (int off = 1; off < BNODES; off <<= 1) {
        int add = 0;
        if (tid < BNODES && tid >= off) add = lcur[tid - off];
        __syncthreads();
        if (tid < BNODES) lcur[tid] += add;
        __syncthreads();
    }

    if (tid < BNODES) {
        int st = lcur[tid] - lhist[tid];           // exclusive
        int node = (b << BSH) + tid;
        if (node < N_NODES) {
            start_g[node] = gbase + st;
            deg_g[node] = lhist[tid];
        }
        lcur[tid] = st;
    }
    __syncthreads();

    for (int j = tid; j < cnt; j += 512) {
        unsigned e = eb[j];
        int p = atomicAdd(&lcur[e >> 18], 1);
        adj[(size_t)gbase + p] = (int)(e & 0x3FFFF); // random only within ~27 KB
    }
}

// ---- E) layer-1 half gather: user/item cols [c,c+32) -> half buf [N,32] ----
__global__ __launch_bounds__(256) void k_gh1(const int* __restrict__ adj,
                                             const int* __restrict__ start_g,
                                             const int* __restrict__ deg_g,
                                             const float* __restrict__ user,
                                             const float* __restrict__ item,
                                             int coloff,
                                             float* __restrict__ half) {
    int gid = blockIdx.x * blockDim.x + threadIdx.x;
    int node = gid >> 5;
    int d = gid & 31;
    if (node >= N_NODES) return;

    int start = start_g[node];
    int end = start + deg_g[node];
    float acc = 0.f;

    int j = start;
    for (; j + 4 <= end; j += 4) {
        int n0 = adj[j + 0], n1 = adj[j + 1], n2 = adj[j + 2], n3 = adj[j + 3];
        const float* p0 = (n0 < NUM_USERS) ? user + (size_t)n0 * EMB_D
                                           : item + (size_t)(n0 - NUM_USERS) * EMB_D;
        const float* p1 = (n1 < NUM_USERS) ? user + (size_t)n1 * EMB_D
                                           : item + (size_t)(n1 - NUM_USERS) * EMB_D;
        const float* p2 = (n2 < NUM_USERS) ? user + (size_t)n2 * EMB_D
                                           : item + (size_t)(n2 - NUM_USERS) * EMB_D;
        const float* p3 = (n3 < NUM_USERS) ? user + (size_t)n3 * EMB_D
                                           : item + (size_t)(n3 - NUM_USERS) * EMB_D;
        acc += p0[coloff + d];
        acc += p1[coloff + d];
        acc += p2[coloff + d];
        acc += p3[coloff + d];
    }
    for (; j < end; ++j) {
        int n = adj[j];
        const float* p = (n < NUM_USERS) ? user + (size_t)n * EMB_D
                                         : item + (size_t)(n - NUM_USERS) * EMB_D;
        acc += p[coloff + d];
    }
    half[(size_t)node * 32 + d] = 0.5f * acc;
}

// ---- F) layer-2 half gather: half buf [N,32] -> out cols [c,c+32) ----
__global__ __launch_bounds__(256) void k_gh2(const int* __restrict__ adj,
                                             const int* __restrict__ start_g,
                                             const int* __restrict__ deg_g,
                                             const float* __restrict__ half,
                                             int coloff,
                                             float* __restrict__ out) {
    int gid = blockIdx.x * blockDim.x + threadIdx.x;
    int node = gid >> 5;
    int d = gid & 31;
    if (node >= N_NODES) return;

    int start = start_g[node];
    int end = start + deg_g[node];
    float acc = 0.f;

    int j = start;
    for (; j + 4 <= end; j += 4) {
        int n0 = adj[j + 0], n1 = adj[j + 1], n2 = adj[j + 2], n3 = adj[j + 3];
        acc += half[(size_t)n0 * 32 + d];
        acc += half[(size_t)n1 * 32 + d];
        acc += half[(size_t)n2 * 32 + d];
        acc += half[(size_t)n3 * 32 + d];
    }
    for (; j < end; ++j) {
        int n = adj[j];
        acc += half[(size_t)n * 32 + d];
    }
    out[(size_t)node * EMB_D + coloff + d] = 0.5f * acc;
}

extern "C" void kernel_launch(void* const* d_in, const int* in_sizes, int n_in,
                              void* d_out, int out_size, void* d_ws, size_t ws_size,
                              hipStream_t stream) {
    const int*   eidx = (const int*)d_in[0];     // [2, NUM_EDGES] int32
    const float* user = (const float*)d_in[1];   // [NUM_USERS, 64]
    const float* item = (const float*)d_in[2];   // [NUM_ITEMS, 64]
    float*       out  = (float*)d_out;           // [N_NODES, 64]

    // workspace — ~37.6 MB
    char* ws = (char*)d_ws;
    size_t off = 0;
    auto alloc = [&](size_t bytes) {
        char* p = ws + off;
        off += (bytes + 255) & ~(size_t)255;
        return p;
    };
    // union: entries (16 MB, dead after k_fill_local) / half (19.2 MB, gathers)
    char*     uni      = alloc((size_t)N_NODES * 32 * sizeof(float));         // 19.2 MB
    unsigned* entries  = (unsigned*)uni;
    float*    half     = (float*)uni;
    int*      adj      = (int*)alloc((size_t)4 * NUM_EDGES * sizeof(int));    // 16 MB
    int*      start_g  = (int*)alloc((size_t)N_NODES * sizeof(int));          // 0.6 MB
    int*      deg_g    = (int*)alloc((size_t)N_NODES * sizeof(int));          // 0.6 MB
    int*      cnt      = (int*)alloc((size_t)NTOT * sizeof(int));             // 1.2 MB
    int*      bsums    = (int*)alloc((size_t)SBLK * sizeof(int));
    int*      boffs    = (int*)alloc((size_t)SBLK * sizeof(int));

    // CSR build: count -> 3-kernel scan -> scatter -> local fill
    k_count<<<P, 256, 0, stream>>>(eidx, cnt);
    k_scan1<<<SBLK, 256, 0, stream>>>(cnt, bsums);
    k_scan2<<<1, 512, 0, stream>>>(bsums, boffs);
    k_scan3<<<(NTOT + 255) / 256, 256, 0, stream>>>(cnt, boffs);
    k_scatter<<<P, 256, 0, stream>>>(eidx, cnt, entries);
    k_fill_local<<<NBUCK, 512, 0, stream>>>(entries, cnt, adj, start_g, deg_g);

    // column-blocked 2-layer propagation (entries dead; half aliases it)
    const int ggh = ((N_NODES * 32) + 255) / 256;  // 18750 blocks
    k_gh1<<<ggh, 256, 0, stream>>>(adj, start_g, deg_g, user, item, 0, half);
    k_gh2<<<ggh, 256, 0, stream>>>(adj, start_g, deg_g, half, 0, out);
    k_gh1<<<ggh, 256, 0, stream>>>(adj, start_g, deg_g, user, item, 32, half);
    k_gh2<<<ggh, 256, 0, stream>>>(adj, start_g, deg_g, half, 32, out);
}

// Round 9
// 438.590 us; speedup vs baseline: 10.5287x; 1.1354x over previous
//
#include <hip/hip_runtime.h>

// LightGCN 2-layer propagation on MI355X — R9: R8 pipeline + VALU-lean
// vectorized gathers.
//
// R8 post-mortem: gathers are the top dispatches (k_gh1 90 us, VALUBusy 53%,
// HBM 33%) — address arithmetic (per-entry user/item pointer select + 64-bit
// adds, 4 B/lane loads) co-limits with memory. R9:
//  (1) fill_local segregates each node's adj into user-prefix + item-suffix
//      (item ids pre-biased by -NUM_USERS; ucnt packed in deg high bits)
//      -> gather loops have FIXED base pointers, no per-entry select.
//  (2) gather = 4 entry-slots x 8 lanes per node; each lane loads float4
//      (global_load_dwordx4, 1 KB/wave instr); float4 acc; 2-step shfl_xor
//      cross-slot reduce. ~3x fewer VALU instrs per 128 B gathered.

#define NUM_USERS 100000
#define NUM_ITEMS 50000
#define N_NODES   150000
#define NUM_EDGES 2000000
#define EMB_D     64

#define BSH    8                                   // 256 nodes per bucket
#define BNODES 256
#define NBUCK  ((N_NODES + BNODES - 1) / BNODES)   // 586
#define P      512                                 // producer blocks
#define CE     ((NUM_EDGES + P - 1) / P)           // 3907 edges per block
#define NTOT   (NBUCK * P)                         // 300032 = 293 * 1024
#define SBLK   (NTOT / 1024)                       // 293 scan blocks

// ---- A) per-block bucket histogram ----
__global__ __launch_bounds__(256) void k_count(const int* __restrict__ eidx,
                                               int* __restrict__ cnt) {
    __shared__ int hist[NBUCK];
    int g = blockIdx.x, tid = threadIdx.x;
    for (int b = tid; b < NBUCK; b += 256) hist[b] = 0;
    __syncthreads();
    int lo = g * CE, hi = min(NUM_EDGES, lo + CE);
    for (int j = lo + tid; j < hi; j += 256) {
        int r = eidx[j], c = eidx[NUM_EDGES + j];
        atomicAdd(&hist[r >> BSH], 1);
        atomicAdd(&hist[c >> BSH], 1);
    }
    __syncthreads();
    for (int b = tid; b < NBUCK; b += 256) cnt[b * P + g] = hist[b];
}

// ---- B1) local exclusive scan: 1024 elems/block (256 thr x 4) ----
__global__ __launch_bounds__(256) void k_scan1(int* __restrict__ cnt,
                                               int* __restrict__ blocksums) {
    __shared__ int lds[256];
    int base = blockIdx.x * 1024 + threadIdx.x * 4;
    int v0 = cnt[base + 0], v1 = cnt[base + 1], v2 = cnt[base + 2], v3 = cnt[base + 3];
    int t = v0 + v1 + v2 + v3;
    lds[threadIdx.x] = t;
    __syncthreads();
    int val = t;
    for (int off = 1; off < 256; off <<= 1) {
        int add = (threadIdx.x >= off) ? lds[threadIdx.x - off] : 0;
        __syncthreads();
        val += add;
        lds[threadIdx.x] = val;
        __syncthreads();
    }
    int run = val - t;
    cnt[base + 0] = run; run += v0;
    cnt[base + 1] = run; run += v1;
    cnt[base + 2] = run; run += v2;
    cnt[base + 3] = run;
    if (threadIdx.x == 255) blocksums[blockIdx.x] = val;
}

// ---- B2) 1-block exclusive scan of 293 partials ----
__global__ __launch_bounds__(512) void k_scan2(const int* __restrict__ blocksums,
                                               int* __restrict__ blockoffs) {
    __shared__ int lds[512];
    int t = threadIdx.x;
    int v = (t < SBLK) ? blocksums[t] : 0;
    lds[t] = v;
    __syncthreads();
    int val = v;
    for (int off = 1; off < 512; off <<= 1) {
        int add = (t >= off) ? lds[t - off] : 0;
        __syncthreads();
        val += add;
        lds[t] = val;
        __syncthreads();
    }
    if (t < SBLK) blockoffs[t] = val - v;
}

// ---- B3) add block offsets ----
__global__ __launch_bounds__(256) void k_scan3(int* __restrict__ cnt,
                                               const int* __restrict__ blockoffs) {
    int i = blockIdx.x * blockDim.x + threadIdx.x;
    if (i < NTOT) cnt[i] += blockoffs[i >> 10];
}

// ---- C) scatter entries into private (bucket, block) slices ----
__global__ __launch_bounds__(256) void k_scatter(const int* __restrict__ eidx,
                                                 const int* __restrict__ cofs,
                                                 unsigned* __restrict__ entries) {
    __shared__ int lcur[NBUCK];
    int g = blockIdx.x, tid = threadIdx.x;
    for (int b = tid; b < NBUCK; b += 256) lcur[b] = cofs[b * P + g];
    __syncthreads();
    int lo = g * CE, hi = min(NUM_EDGES, lo + CE);
    for (int j = lo + tid; j < hi; j += 256) {
        int r = eidx[j], c = eidx[NUM_EDGES + j];
        int p = atomicAdd(&lcur[r >> BSH], 1);
        entries[p] = ((unsigned)(r & 255) << 18) | (unsigned)c;
        int q = atomicAdd(&lcur[c >> BSH], 1);
        entries[q] = ((unsigned)(c & 255) << 18) | (unsigned)r;
    }
}

// ---- D) per-bucket exact CSR with user/item segregation ----
// adj[node] = [user nbr ids ...][item nbr ids - NUM_USERS ...]
// degpack[node] = (ucnt << 16) | deg
__global__ __launch_bounds__(512) void k_fill_local(const unsigned* __restrict__ entries,
                                                    const int* __restrict__ cofs,
                                                    int* __restrict__ adj,
                                                    int* __restrict__ start_g,
                                                    int* __restrict__ degpack) {
    __shared__ int lhU[BNODES];   // user-neighbor count per local node
    __shared__ int lhI[BNODES];   // item-neighbor count
    __shared__ int lsc[BNODES];   // scan scratch (total)
    __shared__ int ucur[BNODES];
    __shared__ int icur[BNODES];
    int b = blockIdx.x, tid = threadIdx.x;
    int gbase = cofs[b * P];
    int gnext = (b + 1 < NBUCK) ? cofs[(b + 1) * P] : 2 * NUM_EDGES;
    int cnt = gnext - gbase;
    const unsigned* eb = entries + gbase;

    if (tid < BNODES) { lhU[tid] = 0; lhI[tid] = 0; }
    __syncthreads();
    for (int j = tid; j < cnt; j += 512) {
        unsigned e = eb[j];
        int nbr = (int)(e & 0x3FFFF);
        int loc = (int)(e >> 18);
        if (nbr < NUM_USERS) atomicAdd(&lhU[loc], 1);
        else                 atomicAdd(&lhI[loc], 1);
    }
    __syncthreads();

    // inclusive scan of total deg
    if (tid < BNODES) lsc[tid] = lhU[tid] + lhI[tid];
    __syncthreads();
    for (int off = 1; off < BNODES; off <<= 1) {
        int add = 0;
        if (tid < BNODES && tid >= off) add = lsc[tid - off];
        __syncthreads();
        if (tid < BNODES) lsc[tid] += add;
        __syncthreads();
    }

    if (tid < BNODES) {
        int deg = lhU[tid] + lhI[tid];
        int st = lsc[tid] - deg;                  // exclusive
        int node = (b << BSH) + tid;
        if (node < N_NODES) {
            start_g[node] = gbase + st;
            degpack[node] = (lhU[tid] << 16) | deg;
        }
        ucur[tid] = st;
        icur[tid] = st + lhU[tid];
    }
    __syncthreads();

    for (int j = tid; j < cnt; j += 512) {
        unsigned e = eb[j];
        int nbr = (int)(e & 0x3FFFF);
        int loc = (int)(e >> 18);
        if (nbr < NUM_USERS) {
            int p = atomicAdd(&ucur[loc], 1);
            adj[(size_t)gbase + p] = nbr;
        } else {
            int p = atomicAdd(&icur[loc], 1);
            adj[(size_t)gbase + p] = nbr - NUM_USERS;   // pre-biased
        }
    }
}

// ---- E/F) vectorized half gather ----
// 32 lanes per node: 4 entry-slots x 8 lanes; lane loads float4 of its
// neighbor's 128 B half-row. Two loops with fixed bases (user part / item
// part). srcA = base for user-ids, srcB = base for (item-id - NUM_USERS).
// strideA/B in floats. Writes [N,32] halfout at dstStride floats per node.
__device__ __forceinline__ void gather_half(const int* __restrict__ adj,
                                            const int* __restrict__ start_g,
                                            const int* __restrict__ degpack,
                                            const float* __restrict__ srcA,
                                            const float* __restrict__ srcB,
                                            float* __restrict__ dst,
                                            int dstStride, int dstOff) {
    int gid = blockIdx.x * blockDim.x + threadIdx.x;
    int node = gid >> 5;
    if (node >= N_NODES) return;
    int grp = threadIdx.x & 31;
    int slot = grp >> 3;          // 0..3 entry slot
    int sub = grp & 7;            // 0..7 -> float4 index within 32 cols

    int start = start_g[node];
    int pack = degpack[node];
    int deg = pack & 0xFFFF;
    int umid = start + (pack >> 16);
    int end = start + deg;

    float4 acc = make_float4(0.f, 0.f, 0.f, 0.f);
    const float* baseA = srcA + sub * 4;
    const float* baseB = srcB + sub * 4;

    // user part [start, umid), slot-strided by 4, unrolled x2
    int j = start + slot;
    for (; j + 4 < umid; j += 8) {
        int n0 = adj[j], n1 = adj[j + 4];
        float4 v0 = *(const float4*)(baseA + (size_t)n0 * EMB_D);
        float4 v1 = *(const float4*)(baseA + (size_t)n1 * EMB_D);
        acc.x += v0.x; acc.y += v0.y; acc.z += v0.z; acc.w += v0.w;
        acc.x += v1.x; acc.y += v1.y; acc.z += v1.z; acc.w += v1.w;
    }
    if (j < umid) {
        int n = adj[j];
        float4 v = *(const float4*)(baseA + (size_t)n * EMB_D);
        acc.x += v.x; acc.y += v.y; acc.z += v.z; acc.w += v.w;
    }
    // item part [umid, end) — ids pre-biased by -NUM_USERS
    j = umid + slot;
    for (; j + 4 < end; j += 8) {
        int n0 = adj[j], n1 = adj[j + 4];
        float4 v0 = *(const float4*)(baseB + (size_t)n0 * EMB_D);
        float4 v1 = *(const float4*)(baseB + (size_t)n1 * EMB_D);
        acc.x += v0.x; acc.y += v0.y; acc.z += v0.z; acc.w += v0.w;
        acc.x += v1.x; acc.y += v1.y; acc.z += v1.z; acc.w += v1.w;
    }
    if (j < end) {
        int n = adj[j];
        float4 v = *(const float4*)(baseB + (size_t)n * EMB_D);
        acc.x += v.x; acc.y += v.y; acc.z += v.z; acc.w += v.w;
    }

    // reduce across the 4 slots (lanes xor 8, 16)
    acc.x += __shfl_xor(acc.x, 8);  acc.y += __shfl_xor(acc.y, 8);
    acc.z += __shfl_xor(acc.z, 8);  acc.w += __shfl_xor(acc.w, 8);
    acc.x += __shfl_xor(acc.x, 16); acc.y += __shfl_xor(acc.y, 16);
    acc.z += __shfl_xor(acc.z, 16); acc.w += __shfl_xor(acc.w, 16);

    if (slot == 0) {
        float4 r = make_float4(0.5f * acc.x, 0.5f * acc.y, 0.5f * acc.z, 0.5f * acc.w);
        *(float4*)(dst + (size_t)node * dstStride + dstOff + sub * 4) = r;
    }
}

// layer 1: user/item tables cols [coloff, coloff+32) -> half buf [N,32]
__global__ __launch_bounds__(256) void k_gh1(const int* __restrict__ adj,
                                             const int* __restrict__ start_g,
                                             const int* __restrict__ degpack,
                                             const float* __restrict__ user,
                                             const float* __restrict__ item,
                                             int coloff,
                                             float* __restrict__ half) {
    gather_half(adj, start_g, degpack, user + coloff, item + coloff,
                half, 32, 0);
}

// layer 2: half buf [N,32] (EMB stride 32) -> out cols [coloff, coloff+32)
__global__ __launch_bounds__(256) void k_gh2(const int* __restrict__ adj,
                                             const int* __restrict__ start_g,
                                             const int* __restrict__ degpack,
                                             const float* __restrict__ halfsrc,
                                             int coloff,
                                             float* __restrict__ out) {
    int gid = blockIdx.x * blockDim.x + threadIdx.x;
    int node = gid >> 5;
    if (node >= N_NODES) return;
    int grp = threadIdx.x & 31;
    int slot = grp >> 3;
    int sub = grp & 7;

    int start = start_g[node];
    int pack = degpack[node];
    int deg = pack & 0xFFFF;
    int umid = start + (pack >> 16);
    int end = start + deg;

    float4 acc = make_float4(0.f, 0.f, 0.f, 0.f);
    const float* baseA = halfsrc + sub * 4;                         // user ids
    const float* baseB = halfsrc + (size_t)NUM_USERS * 32 + sub * 4; // item ids (pre-biased)

    int j = start + slot;
    for (; j + 4 < umid; j += 8) {
        int n0 = adj[j], n1 = adj[j + 4];
        float4 v0 = *(const float4*)(baseA + (size_t)n0 * 32);
        float4 v1 = *(const float4*)(baseA + (size_t)n1 * 32);
        acc.x += v0.x; acc.y += v0.y; acc.z += v0.z; acc.w += v0.w;
        acc.x += v1.x; acc.y += v1.y; acc.z += v1.z; acc.w += v1.w;
    }
    if (j < umid) {
        int n = adj[j];
        float4 v = *(const float4*)(baseA + (size_t)n * 32);
        acc.x += v.x; acc.y += v.y; acc.z += v.z; acc.w += v.w;
    }
    j = umid + slot;
    for (; j + 4 < end; j += 8) {
        int n0 = adj[j], n1 = adj[j + 4];
        float4 v0 = *(const float4*)(baseB + (size_t)n0 * 32);
        float4 v1 = *(const float4*)(baseB + (size_t)n1 * 32);
        acc.x += v0.x; acc.y += v0.y; acc.z += v0.z; acc.w += v0.w;
        acc.x += v1.x; acc.y += v1.y; acc.z += v1.z; acc.w += v1.w;
    }
    if (j < end) {
        int n = adj[j];
        float4 v = *(const float4*)(baseB + (size_t)n * 32);
        acc.x += v.x; acc.y += v.y; acc.z += v.z; acc.w += v.w;
    }

    acc.x += __shfl_xor(acc.x, 8);  acc.y += __shfl_xor(acc.y, 8);
    acc.z += __shfl_xor(acc.z, 8);  acc.w += __shfl_xor(acc.w, 8);
    acc.x += __shfl_xor(acc.x, 16); acc.y += __shfl_xor(acc.y, 16);
    acc.z += __shfl_xor(acc.z, 16); acc.w += __shfl_xor(acc.w, 16);

    if (slot == 0) {
        float4 r = make_float4(0.5f * acc.x, 0.5f * acc.y, 0.5f * acc.z, 0.5f * acc.w);
        *(float4*)(out + (size_t)node * EMB_D + coloff + sub * 4) = r;
    }
}

extern "C" void kernel_launch(void* const* d_in, const int* in_sizes, int n_in,
                              void* d_out, int out_size, void* d_ws, size_t ws_size,
                              hipStream_t stream) {
    const int*   eidx = (const int*)d_in[0];     // [2, NUM_EDGES] int32
    const float* user = (const float*)d_in[1];   // [NUM_USERS, 64]
    const float* item = (const float*)d_in[2];   // [NUM_ITEMS, 64]
    float*       out  = (float*)d_out;           // [N_NODES, 64]

    // workspace — ~37.6 MB
    char* ws = (char*)d_ws;
    size_t off = 0;
    auto alloc = [&](size_t bytes) {
        char* p = ws + off;
        off += (bytes + 255) & ~(size_t)255;
        return p;
    };
    // union: entries (16 MB, dead after k_fill_local) / half (19.2 MB, gathers)
    char*     uni      = alloc((size_t)N_NODES * 32 * sizeof(float));         // 19.2 MB
    unsigned* entries  = (unsigned*)uni;
    float*    half     = (float*)uni;
    int*      adj      = (int*)alloc((size_t)4 * NUM_EDGES * sizeof(int));    // 16 MB
    int*      start_g  = (int*)alloc((size_t)N_NODES * sizeof(int));          // 0.6 MB
    int*      degpack  = (int*)alloc((size_t)N_NODES * sizeof(int));          // 0.6 MB
    int*      cnt      = (int*)alloc((size_t)NTOT * sizeof(int));             // 1.2 MB
    int*      bsums    = (int*)alloc((size_t)SBLK * sizeof(int));
    int*      boffs    = (int*)alloc((size_t)SBLK * sizeof(int));

    // CSR build: count -> 3-kernel scan -> scatter -> local fill
    k_count<<<P, 256, 0, stream>>>(eidx, cnt);
    k_scan1<<<SBLK, 256, 0, stream>>>(cnt, bsums);
    k_scan2<<<1, 512, 0, stream>>>(bsums, boffs);
    k_scan3<<<(NTOT + 255) / 256, 256, 0, stream>>>(cnt, boffs);
    k_scatter<<<P, 256, 0, stream>>>(eidx, cnt, entries);
    k_fill_local<<<NBUCK, 512, 0, stream>>>(entries, cnt, adj, start_g, degpack);

    // column-blocked 2-layer propagation (entries dead; half aliases it)
    const int ggh = ((N_NODES * 32) + 255) / 256;  // 18750 blocks
    k_gh1<<<ggh, 256, 0, stream>>>(adj, start_g, degpack, user, item, 0, half);
    k_gh2<<<ggh, 256, 0, stream>>>(adj, start_g, degpack, half, 0, out);
    k_gh1<<<ggh, 256, 0, stream>>>(adj, start_g, degpack, user, item, 32, half);
    k_gh2<<<ggh, 256, 0, stream>>>(adj, start_g, degpack, half, 32, out);
}